// Round 6
// baseline (264.147 us; speedup 1.0000x reference)
//
#include <hip/hip_runtime.h>
#include <hip/hip_bf16.h>

typedef __hip_bfloat16 bf16;
typedef __attribute__((ext_vector_type(8))) short s8v;   // 8 bf16 MFMA A/B frag
typedef __attribute__((ext_vector_type(4))) float f4v;   // MFMA C/D frag

#define D_MODEL 1024
#define S_LEN   2048
#define BATCH   2
#define NH      16
#define HD      64
#define M_TOTAL 4096

// async global->LDS, 16B/lane; LDS dest = uniform base + lane*16.
// NOTE: the imm offset arg is applied to BOTH global and LDS addresses -> always 0.
#define GLL(gp, lp) __builtin_amdgcn_global_load_lds(                           \
    (const __attribute__((address_space(1))) void*)(gp),                        \
    (__attribute__((address_space(3))) void*)(lp), 16, 0, 0)

// ---------------- fp32 -> bf16 converts ----------------
__global__ __launch_bounds__(256) void cvt_bf16x8(const float* __restrict__ s,
                                                  bf16* __restrict__ d, int n) {
    int i = (blockIdx.x * 256 + threadIdx.x) * 8;
    if (i < n) {
        float4 a = *(const float4*)(s + i);
        float4 b = *(const float4*)(s + i + 4);
        union { bf16 h[8]; uint4 u; } p;
        p.h[0] = __float2bfloat16(a.x); p.h[1] = __float2bfloat16(a.y);
        p.h[2] = __float2bfloat16(a.z); p.h[3] = __float2bfloat16(a.w);
        p.h[4] = __float2bfloat16(b.x); p.h[5] = __float2bfloat16(b.y);
        p.h[6] = __float2bfloat16(b.z); p.h[7] = __float2bfloat16(b.w);
        *(uint4*)(d + i) = p.u;
    }
}

struct WPtrs { const float* s0; const float* s1; const float* s2; const float* s3;
               bf16* d0; bf16* d1; bf16* d2; bf16* d3; };

__global__ __launch_bounds__(256) void cvt_w(WPtrs p) {
    const float* s; bf16* d;
    switch (blockIdx.y) {
        case 0:  s = p.s0; d = p.d0; break;
        case 1:  s = p.s1; d = p.d1; break;
        case 2:  s = p.s2; d = p.d2; break;
        default: s = p.s3; d = p.d3; break;
    }
    int i = (blockIdx.x * 256 + threadIdx.x) * 8;
    float4 a = *(const float4*)(s + i);
    float4 b = *(const float4*)(s + i + 4);
    union { bf16 h[8]; uint4 u; } q;
    q.h[0] = __float2bfloat16(a.x); q.h[1] = __float2bfloat16(a.y);
    q.h[2] = __float2bfloat16(a.z); q.h[3] = __float2bfloat16(a.w);
    q.h[4] = __float2bfloat16(b.x); q.h[5] = __float2bfloat16(b.y);
    q.h[6] = __float2bfloat16(b.z); q.h[7] = __float2bfloat16(b.w);
    *(uint4*)(d + i) = q.u;
}

// ---------------- GEMM main loop (m97 structure) ----------------
// SWAP=false: acc[i][j] row(quad*4+r)=M(x row), col(l15)=N(W row).
// SWAP=true : acc[i][j] row=N (W row, 4 consecutive), col=M.
template<int TM, int TN, bool SWAP>
__device__ __forceinline__ void gemm_loop(const bf16* __restrict__ A,
                                          const bf16* __restrict__ W,
                                          bf16* As, bf16* Bs,
                                          int bm, int bn,
                                          f4v (&acc)[TM/32][TN/32])
{
    constexpr int FM = TM / 32, FN = TN / 32;
    constexpr int CALLS_A = TM / 16, CALLS = (TM + TN) / 16, PW = CALLS / 4;
    const int t = threadIdx.x, wv = t >> 6, lane = t & 63;
    const int quad = lane >> 4, l15 = lane & 15;
    const int wm = (wv >> 1) * (TM / 2), wn = (wv & 1) * (TN / 2);
    const int lr = lane >> 2, lc = (lane & 3) * 8;

    const bf16* aptr[FM];
    const bf16* bptr[FN];
    #pragma unroll
    for (int i = 0; i < FM; ++i) aptr[i] = As + (wm + i * 16 + l15) * 32 + quad * 8;
    #pragma unroll
    for (int j = 0; j < FN; ++j) bptr[j] = Bs + (wn + j * 16 + l15) * 32 + quad * 8;

    const bf16* ag = A + (size_t)(bm + lr) * D_MODEL + lc;
    const bf16* wg = W + (size_t)(bn + lr) * D_MODEL + lc;

    for (int k0 = 0; k0 < D_MODEL; k0 += 32) {
        __syncthreads();
        #pragma unroll
        for (int c = 0; c < PW; ++c) {
            const int cc = wv * PW + c;
            if (cc < CALLS_A) {
                GLL(ag + (size_t)cc * 16 * D_MODEL + k0, As + cc * 512);
            } else {
                const int r2 = cc - CALLS_A;
                GLL(wg + (size_t)r2 * 16 * D_MODEL + k0, Bs + r2 * 512);
            }
        }
        __syncthreads();

        s8v af[FM], bfv[FN];
        #pragma unroll
        for (int i = 0; i < FM; ++i) af[i] = *(const s8v*)aptr[i];
        #pragma unroll
        for (int j = 0; j < FN; ++j) bfv[j] = *(const s8v*)bptr[j];
        #pragma unroll
        for (int i = 0; i < FM; ++i)
            #pragma unroll
            for (int j = 0; j < FN; ++j) {
                if (SWAP)
                    acc[i][j] = __builtin_amdgcn_mfma_f32_16x16x32_bf16(bfv[j], af[i], acc[i][j], 0, 0, 0);
                else
                    acc[i][j] = __builtin_amdgcn_mfma_f32_16x16x32_bf16(af[i], bfv[j], acc[i][j], 0, 0, 0);
            }
    }
}

// Fused QKV: grid (8, 32, 3). z=0 Q (pre-scaled by 0.125), z=1 K: [b][h][s][d],
// swapped orientation -> short4 stores along d. z=2 V^T: [b][h][d][s], normal
// orientation -> short4 stores along s.
__global__ __launch_bounds__(256) void gemm_qkv(
    const bf16* __restrict__ x,
    const bf16* __restrict__ Wq, const bf16* __restrict__ Wk, const bf16* __restrict__ Wv,
    const float* __restrict__ bq, const float* __restrict__ bk, const float* __restrict__ bv,
    bf16* __restrict__ Qb, bf16* __restrict__ Kb, bf16* __restrict__ Vtb)
{
    __shared__ __align__(16) bf16 As[128 * 32];
    __shared__ __align__(16) bf16 Bs[128 * 32];
    const int z = blockIdx.z;
    const bf16*  W    = (z == 0) ? Wq : (z == 1) ? Wk : Wv;
    const float* bias = (z == 0) ? bq : (z == 1) ? bk : bv;
    const int bm = blockIdx.y * 128, bn = blockIdx.x * 128;

    const int t = threadIdx.x, wv = t >> 6, lane = t & 63;
    const int quad = lane >> 4, l15 = lane & 15;
    const int wm = (wv >> 1) * 64, wn = (wv & 1) * 64;

    f4v acc[4][4] = {};
    if (z == 2) {
        gemm_loop<128, 128, false>(x, W, As, Bs, bm, bn, acc);
        // rows = s (4 consecutive), cols = d
        #pragma unroll
        for (int j = 0; j < 4; ++j) {
            const int n = bn + wn + j * 16 + l15;
            const int h = n >> 6, d = n & 63;
            const float bv_ = bias[n];
            #pragma unroll
            for (int i = 0; i < 4; ++i) {
                const int m0 = bm + wm + i * 16 + quad * 4;
                const int b = m0 >> 11, s0 = m0 & 2047;
                union { bf16 hh[4]; short4 s4; } pk;
                #pragma unroll
                for (int r = 0; r < 4; ++r) pk.hh[r] = __float2bfloat16(acc[i][j][r] + bv_);
                *(short4*)&Vtb[(((size_t)(b * NH + h)) * HD + d) * S_LEN + s0] = pk.s4;
            }
        }
    } else {
        gemm_loop<128, 128, true>(x, W, As, Bs, bm, bn, acc);
        bf16* out = (z == 0) ? Qb : Kb;
        const float scale = (z == 0) ? 0.125f : 1.0f;
        // rows = d (4 consecutive), cols = s
        #pragma unroll
        for (int i = 0; i < 4; ++i) {
            const int m = bm + wm + i * 16 + l15;
            const int b = m >> 11, s = m & 2047;
            #pragma unroll
            for (int j = 0; j < 4; ++j) {
                const int n0 = bn + wn + j * 16 + quad * 4;
                const int h = n0 >> 6, d0 = n0 & 63;
                const float4 b4 = *(const float4*)(bias + n0);
                union { bf16 hh[4]; short4 s4; } pk;
                pk.hh[0] = __float2bfloat16((acc[i][j][0] + b4.x) * scale);
                pk.hh[1] = __float2bfloat16((acc[i][j][1] + b4.y) * scale);
                pk.hh[2] = __float2bfloat16((acc[i][j][2] + b4.z) * scale);
                pk.hh[3] = __float2bfloat16((acc[i][j][3] + b4.w) * scale);
                *(short4*)&out[(((size_t)(b * NH + h)) * S_LEN + s) * HD + d0] = pk.s4;
            }
        }
    }
}

// Output projection: 64x128 tiles, fp32 out (coalesced dword stores).
__global__ __launch_bounds__(256) void gemm_out(
    const bf16* __restrict__ Ob, const bf16* __restrict__ Wo,
    const float* __restrict__ bo, float* __restrict__ out)
{
    __shared__ __align__(16) bf16 As[64 * 32];
    __shared__ __align__(16) bf16 Bs[128 * 32];
    const int bm = blockIdx.y * 64, bn = blockIdx.x * 128;

    f4v acc[2][4] = {};
    gemm_loop<64, 128, false>(Ob, Wo, As, Bs, bm, bn, acc);

    const int t = threadIdx.x, wv = t >> 6, lane = t & 63;
    const int quad = lane >> 4, l15 = lane & 15;
    const int wm = (wv >> 1) * 32, wn = (wv & 1) * 64;
    #pragma unroll
    for (int j = 0; j < 4; ++j) {
        const int col = bn + wn + j * 16 + l15;
        const float bv_ = bo[col];
        #pragma unroll
        for (int i = 0; i < 2; ++i)
            #pragma unroll
            for (int r = 0; r < 4; ++r) {
                const int row = bm + wm + i * 16 + quad * 4 + r;
                out[(size_t)row * D_MODEL + col] = acc[i][j][r] + bv_;
            }
    }
}

// ---------------- Flash attention: S^T softmax + O^T accumulation ----------------
// Q pre-scaled by 1/8. S^T = K Q^T: lane owns q=l15, k=c*16+quad*4+r.
// O^T = V^T P^T via mfma(vf, pf): rows=d, cols=q=l15 -> alpha/l are lane-scalar.
// K/V staged via global_load_lds (offset always 0). Per-wave quadrant ownership:
// wave 0: K dims 0-31, wave 1: K dims 32-63, wave 2: V k 0-31, wave 3: V k 32-63.
// Each quadrant = 4 slabs of 16 rows x 32 cols (lane l -> row l>>2, chunk l&3).
__global__ __launch_bounds__(256) void attn_mfma(
    const bf16* __restrict__ Q, const bf16* __restrict__ K,
    const bf16* __restrict__ Vt, const int* __restrict__ mask,
    bf16* __restrict__ O)
{
    __shared__ __align__(16) bf16 KsF[2 * 64 * 32];   // [half d0-31 | half d32-63][krow][32]
    __shared__ __align__(16) bf16 VsF[2 * 64 * 32];   // [half k0-31 | half k32-63][drow][32]
    __shared__ __align__(16) bf16 PsF[4][2 * 16 * 32];
    __shared__ __align__(16) int  msk[64];

    const int t = threadIdx.x, wv = t >> 6, lane = t & 63;
    const int quad = lane >> 4, l15 = lane & 15;
    const int qt = blockIdx.x & 31, h = (blockIdx.x >> 5) & 15, b = blockIdx.x >> 9;
    const int q0 = qt * 64;
    const size_t qkbase = ((size_t)(b * NH + h)) * S_LEN * HD;
    const size_t vtbase = ((size_t)(b * NH + h)) * HD * S_LEN;

    // Q fragments (loop-invariant) straight from global
    const bf16* qrow = Q + qkbase + (size_t)(q0 + wv * 16 + l15) * HD;
    const s8v qf0 = *(const s8v*)(qrow + quad * 8);
    const s8v qf1 = *(const s8v*)(qrow + 32 + quad * 8);

    // per-wave staging quadrant
    const int lr4 = lane >> 2, lc8 = (lane & 3) * 8;
    const bool isK = (wv < 2);
    const bf16* G = isK
        ? (K  + qkbase + (size_t)lr4 * HD    + lc8 + ((wv == 1) ? 32 : 0))
        : (Vt + vtbase + (size_t)lr4 * S_LEN + lc8 + ((wv == 3) ? 32 : 0));
    bf16* Lb = (wv == 0) ? KsF : (wv == 1) ? (KsF + 2048)
             : (wv == 2) ? VsF : (VsF + 2048);
    const size_t gstride = isK ? (size_t)16 * HD : (size_t)16 * S_LEN;  // slab->slab
    const size_t gadv    = isK ? (size_t)64 * HD : (size_t)64;          // tile->tile
    const int* mrow = mask + b * S_LEN + (t & 63);

    float mprev = -1e30f, lsum = 0.f;   // state for q = l15 (row q0+wv*16+l15)
    f4v oacc[4] = {};                   // O^T: rows d = dt*16+quad*4+r, col q=l15

    for (int kt = 0; kt < S_LEN / 64; ++kt) {
        __syncthreads();   // previous tile's LDS consumers done
        GLL(G,               Lb);
        GLL(G + gstride,     Lb + 512);
        GLL(G + 2 * gstride, Lb + 1024);
        GLL(G + 3 * gstride, Lb + 1536);
        if (t < 64) msk[t] = mrow[kt * 64];
        __syncthreads();   // drains vmcnt(0) per wave + barrier

        G += gadv;

        // ---- S^T: rows k-local (c*16+quad*4+r), cols q=l15 ----
        f4v st[4];
        #pragma unroll
        for (int c = 0; c < 4; ++c) {
            s8v kf0 = *(const s8v*)&KsF[(c * 16 + l15) * 32 + quad * 8];
            s8v kf1 = *(const s8v*)&KsF[2048 + (c * 16 + l15) * 32 + quad * 8];
            f4v z = {0.f, 0.f, 0.f, 0.f};
            z = __builtin_amdgcn_mfma_f32_16x16x32_bf16(kf0, qf0, z, 0, 0, 0);
            z = __builtin_amdgcn_mfma_f32_16x16x32_bf16(kf1, qf1, z, 0, 0, 0);
            st[c] = z;
        }

        // ---- mask + max over this lane's 16 k (Q pre-scaled: no mul) ----
        float mt = -1e30f;
        #pragma unroll
        for (int c = 0; c < 4; ++c) {
            const int4 mk = *(const int4*)&msk[c * 16 + quad * 4];
            float v0 = st[c][0]; if (mk.x == 0) v0 = -1e10f;
            float v1 = st[c][1]; if (mk.y == 0) v1 = -1e10f;
            float v2 = st[c][2]; if (mk.z == 0) v2 = -1e10f;
            float v3 = st[c][3]; if (mk.w == 0) v3 = -1e10f;
            st[c][0] = v0; st[c][1] = v1; st[c][2] = v2; st[c][3] = v3;
            mt = fmaxf(mt, fmaxf(fmaxf(v0, v1), fmaxf(v2, v3)));
        }
        mt = fmaxf(mt, __shfl_xor(mt, 16, 64));
        mt = fmaxf(mt, __shfl_xor(mt, 32, 64));

        const float mn = fmaxf(mprev, mt);
        const float alpha = __expf(mprev - mn);
        mprev = mn;

        float ps = 0.f;
        #pragma unroll
        for (int c = 0; c < 4; ++c) {
            #pragma unroll
            for (int r = 0; r < 4; ++r) {
                const float p = __expf(st[c][r] - mn);
                st[c][r] = p;
                ps += p;
            }
        }
        ps += __shfl_xor(ps, 16, 64);
        ps += __shfl_xor(ps, 32, 64);
        lsum = lsum * alpha + ps;

        // ---- P -> per-wave LDS [q=l15][k] (two halves), short4 packed ----
        #pragma unroll
        for (int c = 0; c < 4; ++c) {
            union { bf16 hh[4]; short4 s4; } pk;
            pk.hh[0] = __float2bfloat16(st[c][0]);
            pk.hh[1] = __float2bfloat16(st[c][1]);
            pk.hh[2] = __float2bfloat16(st[c][2]);
            pk.hh[3] = __float2bfloat16(st[c][3]);
            *(short4*)&PsF[wv][(c >> 1) * 512 + l15 * 32 + (c & 1) * 16 + quad * 4] = pk.s4;
        }

        // ---- O^T rescale by own-lane alpha, then O^T += V^T P^T ----
        #pragma unroll
        for (int dt = 0; dt < 4; ++dt)
            #pragma unroll
            for (int r = 0; r < 4; ++r) oacc[dt][r] *= alpha;

        s8v pf0 = *(const s8v*)&PsF[wv][l15 * 32 + quad * 8];
        s8v pf1 = *(const s8v*)&PsF[wv][512 + l15 * 32 + quad * 8];
        #pragma unroll
        for (int dt = 0; dt < 4; ++dt) {
            s8v vf0 = *(const s8v*)&VsF[(dt * 16 + l15) * 32 + quad * 8];
            s8v vf1 = *(const s8v*)&VsF[2048 + (dt * 16 + l15) * 32 + quad * 8];
            oacc[dt] = __builtin_amdgcn_mfma_f32_16x16x32_bf16(vf0, pf0, oacc[dt], 0, 0, 0);
            oacc[dt] = __builtin_amdgcn_mfma_f32_16x16x32_bf16(vf1, pf1, oacc[dt], 0, 0, 0);
        }
    }

    // ---- epilogue: lane owns q=l15; rows d contiguous -> short4 stores ----
    const float linv = 1.f / lsum;
    const int s = q0 + wv * 16 + l15;
    bf16* orow = O + ((size_t)b * S_LEN + s) * D_MODEL + h * 64;
    #pragma unroll
    for (int dt = 0; dt < 4; ++dt) {
        union { bf16 hh[4]; short4 s4; } pk;
        #pragma unroll
        for (int r = 0; r < 4; ++r) pk.hh[r] = __float2bfloat16(oacc[dt][r] * linv);
        *(short4*)&orow[dt * 16 + quad * 4] = pk.s4;
    }
}

extern "C" void kernel_launch(void* const* d_in, const int* in_sizes, int n_in,
                              void* d_out, int out_size, void* d_ws, size_t ws_size,
                              hipStream_t stream) {
    const float* x    = (const float*)d_in[0];
    const int*   mask = (const int*)  d_in[1];
    const float* Wq   = (const float*)d_in[2];
    const float* bq   = (const float*)d_in[3];
    const float* Wk   = (const float*)d_in[4];
    const float* bk   = (const float*)d_in[5];
    const float* Wv   = (const float*)d_in[6];
    const float* bv   = (const float*)d_in[7];
    const float* Wo   = (const float*)d_in[8];
    const float* bo   = (const float*)d_in[9];
    float* out = (float*)d_out;

    char* w = (char*)d_ws;
    bf16* xb  = (bf16*)w; w += (size_t)M_TOTAL * D_MODEL * 2;
    bf16* Wqb = (bf16*)w; w += (size_t)D_MODEL * D_MODEL * 2;
    bf16* Wkb = (bf16*)w; w += (size_t)D_MODEL * D_MODEL * 2;
    bf16* Wvb = (bf16*)w; w += (size_t)D_MODEL * D_MODEL * 2;
    bf16* Wob = (bf16*)w; w += (size_t)D_MODEL * D_MODEL * 2;
    bf16* Qb  = (bf16*)w; w += (size_t)M_TOTAL * D_MODEL * 2;   // [b][h][s][d], pre-scaled
    bf16* Kb  = (bf16*)w; w += (size_t)M_TOTAL * D_MODEL * 2;   // [b][h][s][d]
    bf16* Vtb = (bf16*)w; w += (size_t)M_TOTAL * D_MODEL * 2;   // [b][h][d][s]
    bf16* Ob  = (bf16*)w; w += (size_t)M_TOTAL * D_MODEL * 2;   // [b][s][1024]

    const int nx = M_TOTAL * D_MODEL;
    cvt_bf16x8<<<nx / 2048, 256, 0, stream>>>(x, xb, nx);
    WPtrs wp = { Wq, Wk, Wv, Wo, Wqb, Wkb, Wvb, Wob };
    cvt_w<<<dim3(D_MODEL * D_MODEL / 2048, 4), 256, 0, stream>>>(wp);

    gemm_qkv<<<dim3(8, 32, 3), 256, 0, stream>>>(xb, Wqb, Wkb, Wvb, bq, bk, bv, Qb, Kb, Vtb);

    attn_mfma<<<BATCH * NH * (S_LEN / 64), 256, 0, stream>>>(Qb, Kb, Vtb, mask, Ob);

    gemm_out<<<dim3(8, 64), 256, 0, stream>>>(Ob, Wob, bo, out);
}

// Round 8
// 260.240 us; speedup vs baseline: 1.0150x; 1.0150x over previous
//
#include <hip/hip_runtime.h>
#include <hip/hip_bf16.h>

typedef __hip_bfloat16 bf16;
typedef __attribute__((ext_vector_type(8))) short s8v;   // 8 bf16 MFMA A/B frag
typedef __attribute__((ext_vector_type(4))) float f4v;   // MFMA C/D frag

#define D_MODEL 1024
#define S_LEN   2048
#define BATCH   2
#define NH      16
#define HD      64
#define M_TOTAL 4096

// async global->LDS, 16B/lane; LDS dest = uniform base + lane*16. imm offset
// applies to BOTH addresses -> always 0, all deltas via pointers.
#define GLL(gp, lp) __builtin_amdgcn_global_load_lds(                           \
    (const __attribute__((address_space(1))) void*)(gp),                        \
    (__attribute__((address_space(3))) void*)(lp), 16, 0, 0)

// ---------------- fused fp32 -> bf16 convert (x + 4 weights, one launch) ----
struct CvtArgs {
    const float* s[5];
    bf16* d[5];
};
__global__ __launch_bounds__(256) void cvt_all(CvtArgs a) {
    const int bx = blockIdx.x;
    int which, lb;
    if (bx < 2048) { which = 0; lb = bx; }            // x: 4M elems = 2048 blocks
    else { which = 1 + ((bx - 2048) >> 9); lb = (bx - 2048) & 511; }  // W: 512 each
    const float* s = a.s[which];
    bf16* d = a.d[which];
    const int i = lb * 2048 + threadIdx.x * 8;
    float4 v0 = *(const float4*)(s + i);
    float4 v1 = *(const float4*)(s + i + 4);
    union { bf16 h[8]; uint4 u; } p;
    p.h[0] = __float2bfloat16(v0.x); p.h[1] = __float2bfloat16(v0.y);
    p.h[2] = __float2bfloat16(v0.z); p.h[3] = __float2bfloat16(v0.w);
    p.h[4] = __float2bfloat16(v1.x); p.h[5] = __float2bfloat16(v1.y);
    p.h[6] = __float2bfloat16(v1.z); p.h[7] = __float2bfloat16(v1.w);
    *(uint4*)(d + i) = p.u;
}

// ---------------- GEMM main loop (m97 structure) ----------------
// SWAP=false: acc[i][j] row(quad*4+r)=M(x row), col(l15)=N(W row).
// SWAP=true : acc[i][j] row=N (W row, 4 consecutive), col=M.
template<int TM, int TN, bool SWAP>
__device__ __forceinline__ void gemm_loop(const bf16* __restrict__ A,
                                          const bf16* __restrict__ W,
                                          bf16* As, bf16* Bs,
                                          int bm, int bn,
                                          f4v (&acc)[TM/32][TN/32])
{
    constexpr int FM = TM / 32, FN = TN / 32;
    constexpr int CALLS_A = TM / 16, CALLS = (TM + TN) / 16, PW = CALLS / 4;
    const int t = threadIdx.x, wv = t >> 6, lane = t & 63;
    const int quad = lane >> 4, l15 = lane & 15;
    const int wm = (wv >> 1) * (TM / 2), wn = (wv & 1) * (TN / 2);
    const int lr = lane >> 2, lc = (lane & 3) * 8;

    const bf16* aptr[FM];
    const bf16* bptr[FN];
    #pragma unroll
    for (int i = 0; i < FM; ++i) aptr[i] = As + (wm + i * 16 + l15) * 32 + quad * 8;
    #pragma unroll
    for (int j = 0; j < FN; ++j) bptr[j] = Bs + (wn + j * 16 + l15) * 32 + quad * 8;

    const bf16* ag = A + (size_t)(bm + lr) * D_MODEL + lc;
    const bf16* wg = W + (size_t)(bn + lr) * D_MODEL + lc;

    for (int k0 = 0; k0 < D_MODEL; k0 += 32) {
        __syncthreads();
        #pragma unroll
        for (int c = 0; c < PW; ++c) {
            const int cc = wv * PW + c;
            if (cc < CALLS_A) {
                GLL(ag + (size_t)cc * 16 * D_MODEL + k0, As + cc * 512);
            } else {
                const int r2 = cc - CALLS_A;
                GLL(wg + (size_t)r2 * 16 * D_MODEL + k0, Bs + r2 * 512);
            }
        }
        __syncthreads();

        s8v af[FM], bfv[FN];
        #pragma unroll
        for (int i = 0; i < FM; ++i) af[i] = *(const s8v*)aptr[i];
        #pragma unroll
        for (int j = 0; j < FN; ++j) bfv[j] = *(const s8v*)bptr[j];
        #pragma unroll
        for (int i = 0; i < FM; ++i)
            #pragma unroll
            for (int j = 0; j < FN; ++j) {
                if (SWAP)
                    acc[i][j] = __builtin_amdgcn_mfma_f32_16x16x32_bf16(bfv[j], af[i], acc[i][j], 0, 0, 0);
                else
                    acc[i][j] = __builtin_amdgcn_mfma_f32_16x16x32_bf16(af[i], bfv[j], acc[i][j], 0, 0, 0);
            }
    }
}

// Fused QKV: grid (8, 32, 3). z=0 Q (pre-scaled by 0.125), z=1 K: [b][h][s][d],
// swapped orientation -> short4 stores along d. z=2 V^T: [b][h][d][s].
__global__ __launch_bounds__(256) void gemm_qkv(
    const bf16* __restrict__ x,
    const bf16* __restrict__ Wq, const bf16* __restrict__ Wk, const bf16* __restrict__ Wv,
    const float* __restrict__ bq, const float* __restrict__ bk, const float* __restrict__ bv,
    bf16* __restrict__ Qb, bf16* __restrict__ Kb, bf16* __restrict__ Vtb)
{
    __shared__ __align__(16) bf16 As[128 * 32];
    __shared__ __align__(16) bf16 Bs[128 * 32];
    const int z = blockIdx.z;
    const bf16*  W    = (z == 0) ? Wq : (z == 1) ? Wk : Wv;
    const float* bias = (z == 0) ? bq : (z == 1) ? bk : bv;
    const int bm = blockIdx.y * 128, bn = blockIdx.x * 128;

    const int t = threadIdx.x, wv = t >> 6, lane = t & 63;
    const int quad = lane >> 4, l15 = lane & 15;
    const int wm = (wv >> 1) * 64, wn = (wv & 1) * 64;

    f4v acc[4][4] = {};
    if (z == 2) {
        gemm_loop<128, 128, false>(x, W, As, Bs, bm, bn, acc);
        #pragma unroll
        for (int j = 0; j < 4; ++j) {
            const int n = bn + wn + j * 16 + l15;
            const int h = n >> 6, d = n & 63;
            const float bv_ = bias[n];
            #pragma unroll
            for (int i = 0; i < 4; ++i) {
                const int m0 = bm + wm + i * 16 + quad * 4;
                const int b = m0 >> 11, s0 = m0 & 2047;
                union { bf16 hh[4]; short4 s4; } pk;
                #pragma unroll
                for (int r = 0; r < 4; ++r) pk.hh[r] = __float2bfloat16(acc[i][j][r] + bv_);
                *(short4*)&Vtb[(((size_t)(b * NH + h)) * HD + d) * S_LEN + s0] = pk.s4;
            }
        }
    } else {
        gemm_loop<128, 128, true>(x, W, As, Bs, bm, bn, acc);
        bf16* out = (z == 0) ? Qb : Kb;
        const float scale = (z == 0) ? 0.125f : 1.0f;
        #pragma unroll
        for (int i = 0; i < 4; ++i) {
            const int m = bm + wm + i * 16 + l15;
            const int b = m >> 11, s = m & 2047;
            #pragma unroll
            for (int j = 0; j < 4; ++j) {
                const int n0 = bn + wn + j * 16 + quad * 4;
                const int h = n0 >> 6, d0 = n0 & 63;
                const float4 b4 = *(const float4*)(bias + n0);
                union { bf16 hh[4]; short4 s4; } pk;
                pk.hh[0] = __float2bfloat16((acc[i][j][0] + b4.x) * scale);
                pk.hh[1] = __float2bfloat16((acc[i][j][1] + b4.y) * scale);
                pk.hh[2] = __float2bfloat16((acc[i][j][2] + b4.z) * scale);
                pk.hh[3] = __float2bfloat16((acc[i][j][3] + b4.w) * scale);
                *(short4*)&out[(((size_t)(b * NH + h)) * S_LEN + s) * HD + d0] = pk.s4;
            }
        }
    }
}

// Output projection: 64x128 tiles, fp32 out.
__global__ __launch_bounds__(256) void gemm_out(
    const bf16* __restrict__ Ob, const bf16* __restrict__ Wo,
    const float* __restrict__ bo, float* __restrict__ out)
{
    __shared__ __align__(16) bf16 As[64 * 32];
    __shared__ __align__(16) bf16 Bs[128 * 32];
    const int bm = blockIdx.y * 64, bn = blockIdx.x * 128;

    f4v acc[2][4] = {};
    gemm_loop<64, 128, false>(Ob, Wo, As, Bs, bm, bn, acc);

    const int t = threadIdx.x, wv = t >> 6, lane = t & 63;
    const int quad = lane >> 4, l15 = lane & 15;
    const int wm = (wv >> 1) * 32, wn = (wv & 1) * 64;
    #pragma unroll
    for (int j = 0; j < 4; ++j) {
        const int col = bn + wn + j * 16 + l15;
        const float bv_ = bo[col];
        #pragma unroll
        for (int i = 0; i < 2; ++i)
            #pragma unroll
            for (int r = 0; r < 4; ++r) {
                const int row = bm + wm + i * 16 + quad * 4 + r;
                out[(size_t)row * D_MODEL + col] = acc[i][j][r] + bv_;
            }
    }
}

// ---------------- Flash attention v3.1 ----------------
// Block = 128 thr (2 waves), 64 q. Wave wv owns q rows wv*32..wv*32+31 (2 groups
// of 16). Wave 0 stages K, wave 1 stages V via permuted GLL: lane l -> global
// (row l&15, chunk l>>4) so frag-read bank = l15*4%32 (consecutive 8 lanes tile
// all 32 banks -> conflict-free). K/V double-buffered, ONE barrier per tile.
// P buffer: per-wave 16 rows x stride 72 (64 payload + 8 pad), shared across
// the two q-groups (same-wave DS ordering).
__global__ __launch_bounds__(128) void attn_mfma(
    const bf16* __restrict__ Q, const bf16* __restrict__ K,
    const bf16* __restrict__ Vt, const int* __restrict__ mask,
    bf16* __restrict__ O)
{
    __shared__ __align__(16) bf16 KsF[2 * 4096];   // [buf][hf d-half][slab c][512]
    __shared__ __align__(16) bf16 VsF[2 * 4096];   // [buf][hf k-half][slab dt][512]
    __shared__ __align__(16) bf16 PsF[2][16 * 72]; // per-wave P: [q l15][k 0..63], stride 72

    const int t = threadIdx.x, wv = t >> 6, lane = t & 63;
    const int quad = lane >> 4, l15 = lane & 15;
    const int qt = blockIdx.x & 31, h = (blockIdx.x >> 5) & 15, b = blockIdx.x >> 9;
    const int q0 = qt * 64;
    const size_t qkbase = ((size_t)(b * NH + h)) * S_LEN * HD;
    const size_t vtbase = ((size_t)(b * NH + h)) * HD * S_LEN;

    // Q fragments (loop-invariant) straight from global; Q pre-scaled by 1/8
    s8v qf[2][2];
    #pragma unroll
    for (int qg = 0; qg < 2; ++qg) {
        const bf16* qrow = Q + qkbase + (size_t)(q0 + wv * 32 + qg * 16 + l15) * HD;
        qf[qg][0] = *(const s8v*)(qrow + quad * 8);
        qf[qg][1] = *(const s8v*)(qrow + 32 + quad * 8);
    }

    // permuted staging: lane l -> global (row l&15, chunk l>>4) of a 16x32 slab
    const bool isV = (wv == 1);
    const bf16* gb = isV ? (Vt + vtbase + (size_t)(lane & 15) * S_LEN + (lane >> 4) * 8)
                         : (K  + qkbase + (size_t)(lane & 15) * HD    + (lane >> 4) * 8);
    const size_t gslab = isV ? (size_t)(16 * S_LEN) : (size_t)(16 * HD);
    const size_t gadv  = isV ? (size_t)64 : (size_t)(64 * HD);
    bf16* lb = isV ? VsF : KsF;

    {   // stage tile 0 -> buf 0
        #pragma unroll
        for (int hf = 0; hf < 2; ++hf)
            #pragma unroll
            for (int gg = 0; gg < 4; ++gg)
                GLL(gb + hf * 32 + gg * gslab, lb + hf * 2048 + gg * 512);
    }
    const bf16* gpre = gb + gadv;

    const int* mbase = mask + b * S_LEN + quad * 4;

    float mprev[2] = {-1e30f, -1e30f}, lsum[2] = {0.f, 0.f};
    f4v oacc[2][4] = {};   // [qg][dt]: O^T rows d=dt*16+quad*4+r, col q=l15

    for (int kt = 0; kt < S_LEN / 64; ++kt) {
        __syncthreads();   // buf[kt&1] DMA done; tile kt-1 readers done
        {   // prefetch tile kt+1 -> other buffer
            bf16* l = lb + ((kt + 1) & 1) * 4096;
            #pragma unroll
            for (int hf = 0; hf < 2; ++hf)
                #pragma unroll
                for (int gg = 0; gg < 4; ++gg)
                    GLL(gpre + hf * 32 + gg * gslab, l + hf * 2048 + gg * 512);
        }
        gpre += gadv;
        const int cb = (kt & 1) * 4096;

        int4 mk[4];
        #pragma unroll
        for (int c = 0; c < 4; ++c) mk[c] = *(const int4*)(mbase + kt * 64 + c * 16);

        #pragma unroll
        for (int qg = 0; qg < 2; ++qg) {
            // ---- S^T: rows k=c*16+quad*4+r, col q=l15 ----
            f4v st[4];
            #pragma unroll
            for (int c = 0; c < 4; ++c) {
                s8v kf0 = *(const s8v*)&KsF[cb + c * 512 + quad * 128 + l15 * 8];
                s8v kf1 = *(const s8v*)&KsF[cb + 2048 + c * 512 + quad * 128 + l15 * 8];
                f4v z = {0.f, 0.f, 0.f, 0.f};
                z = __builtin_amdgcn_mfma_f32_16x16x32_bf16(kf0, qf[qg][0], z, 0, 0, 0);
                z = __builtin_amdgcn_mfma_f32_16x16x32_bf16(kf1, qf[qg][1], z, 0, 0, 0);
                st[c] = z;
            }

            // ---- mask + in-register max over this lane's 16 k ----
            float mt = -1e30f;
            #pragma unroll
            for (int c = 0; c < 4; ++c) {
                float v0 = st[c][0]; if (mk[c].x == 0) v0 = -1e10f;
                float v1 = st[c][1]; if (mk[c].y == 0) v1 = -1e10f;
                float v2 = st[c][2]; if (mk[c].z == 0) v2 = -1e10f;
                float v3 = st[c][3]; if (mk[c].w == 0) v3 = -1e10f;
                st[c][0] = v0; st[c][1] = v1; st[c][2] = v2; st[c][3] = v3;
                mt = fmaxf(mt, fmaxf(fmaxf(v0, v1), fmaxf(v2, v3)));
            }
            mt = fmaxf(mt, __shfl_xor(mt, 16, 64));
            mt = fmaxf(mt, __shfl_xor(mt, 32, 64));

            const float mn = fmaxf(mprev[qg], mt);
            const float alpha = __expf(mprev[qg] - mn);
            mprev[qg] = mn;

            float ps = 0.f;
            #pragma unroll
            for (int c = 0; c < 4; ++c) {
                #pragma unroll
                for (int r = 0; r < 4; ++r) {
                    const float p = __expf(st[c][r] - mn);
                    st[c][r] = p;
                    ps += p;
                }
            }
            ps += __shfl_xor(ps, 16, 64);
            ps += __shfl_xor(ps, 32, 64);
            lsum[qg] = lsum[qg] * alpha + ps;

            // ---- P -> per-wave LDS [q=l15][k], stride 72 ----
            #pragma unroll
            for (int c = 0; c < 4; ++c) {
                union { bf16 hh[4]; short4 s4; } pk;
                pk.hh[0] = __float2bfloat16(st[c][0]);
                pk.hh[1] = __float2bfloat16(st[c][1]);
                pk.hh[2] = __float2bfloat16(st[c][2]);
                pk.hh[3] = __float2bfloat16(st[c][3]);
                *(short4*)&PsF[wv][l15 * 72 + c * 16 + quad * 4] = pk.s4;
            }

            // ---- O^T rescale (lane-scalar alpha), then O^T += V^T P^T ----
            #pragma unroll
            for (int dt = 0; dt < 4; ++dt)
                #pragma unroll
                for (int r = 0; r < 4; ++r) oacc[qg][dt][r] *= alpha;

            s8v pf0 = *(const s8v*)&PsF[wv][l15 * 72 + quad * 8];
            s8v pf1 = *(const s8v*)&PsF[wv][l15 * 72 + 32 + quad * 8];
            #pragma unroll
            for (int dt = 0; dt < 4; ++dt) {
                s8v vf0 = *(const s8v*)&VsF[cb + dt * 512 + quad * 128 + l15 * 8];
                s8v vf1 = *(const s8v*)&VsF[cb + 2048 + dt * 512 + quad * 128 + l15 * 8];
                oacc[qg][dt] = __builtin_amdgcn_mfma_f32_16x16x32_bf16(vf0, pf0, oacc[qg][dt], 0, 0, 0);
                oacc[qg][dt] = __builtin_amdgcn_mfma_f32_16x16x32_bf16(vf1, pf1, oacc[qg][dt], 0, 0, 0);
            }
        }
    }

    // ---- epilogue ----
    #pragma unroll
    for (int qg = 0; qg < 2; ++qg) {
        const float linv = 1.f / lsum[qg];
        const int s = q0 + wv * 32 + qg * 16 + l15;
        bf16* orow = O + ((size_t)b * S_LEN + s) * D_MODEL + h * 64;
        #pragma unroll
        for (int dt = 0; dt < 4; ++dt) {
            union { bf16 hh[4]; short4 s4; } pk;
            #pragma unroll
            for (int r = 0; r < 4; ++r) pk.hh[r] = __float2bfloat16(oacc[qg][dt][r] * linv);
            *(short4*)&orow[dt * 16 + quad * 4] = pk.s4;
        }
    }
}

extern "C" void kernel_launch(void* const* d_in, const int* in_sizes, int n_in,
                              void* d_out, int out_size, void* d_ws, size_t ws_size,
                              hipStream_t stream) {
    const float* x    = (const float*)d_in[0];
    const int*   mask = (const int*)  d_in[1];
    const float* Wq   = (const float*)d_in[2];
    const float* bq   = (const float*)d_in[3];
    const float* Wk   = (const float*)d_in[4];
    const float* bk   = (const float*)d_in[5];
    const float* Wv   = (const float*)d_in[6];
    const float* bv   = (const float*)d_in[7];
    const float* Wo   = (const float*)d_in[8];
    const float* bo   = (const float*)d_in[9];
    float* out = (float*)d_out;

    char* w = (char*)d_ws;
    bf16* xb  = (bf16*)w; w += (size_t)M_TOTAL * D_MODEL * 2;
    bf16* Wqb = (bf16*)w; w += (size_t)D_MODEL * D_MODEL * 2;
    bf16* Wkb = (bf16*)w; w += (size_t)D_MODEL * D_MODEL * 2;
    bf16* Wvb = (bf16*)w; w += (size_t)D_MODEL * D_MODEL * 2;
    bf16* Wob = (bf16*)w; w += (size_t)D_MODEL * D_MODEL * 2;
    bf16* Qb  = (bf16*)w; w += (size_t)M_TOTAL * D_MODEL * 2;   // [b][h][s][d], pre-scaled
    bf16* Kb  = (bf16*)w; w += (size_t)M_TOTAL * D_MODEL * 2;   // [b][h][s][d]
    bf16* Vtb = (bf16*)w; w += (size_t)M_TOTAL * D_MODEL * 2;   // [b][h][d][s]
    bf16* Ob  = (bf16*)w; w += (size_t)M_TOTAL * D_MODEL * 2;   // [b][s][1024]

    CvtArgs ca;
    ca.s[0] = x;  ca.s[1] = Wq;  ca.s[2] = Wk;  ca.s[3] = Wv;  ca.s[4] = Wo;
    ca.d[0] = xb; ca.d[1] = Wqb; ca.d[2] = Wkb; ca.d[3] = Wvb; ca.d[4] = Wob;
    cvt_all<<<2048 + 4 * 512, 256, 0, stream>>>(ca);

    gemm_qkv<<<dim3(8, 32, 3), 256, 0, stream>>>(xb, Wqb, Wkb, Wvb, bq, bk, bv, Qb, Kb, Vtb);

    attn_mfma<<<BATCH * NH * (S_LEN / 64), 128, 0, stream>>>(Qb, Kb, Vtb, mask, Ob);

    gemm_out<<<dim3(8, 64), 256, 0, stream>>>(Ob, Wob, bo, out);
}